// Round 1
// baseline (26.697 us; speedup 1.0000x reference)
//
#include <hip/hip_runtime.h>
#include <math.h>

#define NCH 8
#define KMIX 4
#define TRI 36           // 8*9/2
#define CSTRIDE 48       // per-component constant stride (36 Linv + 8 b + 1 c, padded)
#define LOG_2PI 1.8378770664093453f

// ---------------------------------------------------------------------------
// Setup kernel: 4 threads, one per mixture component k.
// Computes Linv = L^{-1} (lower-tri, packed row-major tril), b = Linv @ mu,
// and c = log_softmax(w)_k - log det L_k - 0.5*N*log(2pi) into ws[k*48 + ...].
// ---------------------------------------------------------------------------
__global__ void gmm_setup(const float* __restrict__ weights,
                          const float* __restrict__ loc,          // [N, K]
                          const float* __restrict__ sp,           // [TRI, K]
                          float* __restrict__ ws) {
    int k = threadIdx.x;
    if (k >= KMIX) return;

    // log_softmax of weights (stable)
    float wmax = weights[0];
    for (int i = 1; i < KMIX; ++i) wmax = fmaxf(wmax, weights[i]);
    float se = 0.f;
    for (int i = 0; i < KMIX; ++i) se += expf(weights[i] - wmax);
    float logw = weights[k] - (wmax + logf(se));

    // unpack L (lower triangular, row-major tril order)
    float L[NCH][NCH];
    int t = 0;
    for (int i = 0; i < NCH; ++i)
        for (int j = 0; j <= i; ++j)
            L[i][j] = sp[t++ * KMIX + k];

    float logdet = 0.f;
    for (int i = 0; i < NCH; ++i) logdet += logf(L[i][i]);

    // invert lower triangular: solve L * Li = I column by column
    float Li[NCH][NCH];
    for (int j = 0; j < NCH; ++j) {
        for (int i = j; i < NCH; ++i) {
            float s = (i == j) ? 1.f : 0.f;
            for (int m = j; m < i; ++m) s -= L[i][m] * Li[m][j];
            Li[i][j] = s / L[i][i];
        }
    }

    // mu_k = loc[:, k]
    float mu[NCH];
    for (int j = 0; j < NCH; ++j) mu[j] = loc[j * KMIX + k];

    float* o = ws + k * CSTRIDE;
    t = 0;
    for (int i = 0; i < NCH; ++i)
        for (int j = 0; j <= i; ++j)
            o[t++] = Li[i][j];
    for (int i = 0; i < NCH; ++i) {
        float b = 0.f;
        for (int j = 0; j <= i; ++j) b += Li[i][j] * mu[j];
        o[TRI + i] = b;
    }
    o[44] = logw - logdet - 0.5f * NCH * LOG_2PI;
}

// ---------------------------------------------------------------------------
// Main kernel: 1 voxel per thread. Streaming, memory-bound.
// ---------------------------------------------------------------------------
__global__ __launch_bounds__(256) void gmm_main(const float* __restrict__ x,
                                                const float* __restrict__ cst,
                                                float* __restrict__ out,
                                                int B) {
    int v = blockIdx.x * blockDim.x + threadIdx.x;
    if (v >= B) return;

    const float4* xp = reinterpret_cast<const float4*>(x + (size_t)v * NCH);
    float4 a0 = xp[0];
    float4 a1 = xp[1];
    float xv[NCH] = {a0.x, a0.y, a0.z, a0.w, a1.x, a1.y, a1.z, a1.w};

    float lp[KMIX];
#pragma unroll
    for (int k = 0; k < KMIX; ++k) {
        const float* c = cst + k * CSTRIDE;   // uniform address, const offsets -> s_load
        float maha = 0.f;
        int t = 0;
#pragma unroll
        for (int i = 0; i < NCH; ++i) {
            float z = -c[TRI + i];            // z_i = Linv row_i . x - b_i
#pragma unroll
            for (int j = 0; j <= i; ++j) {
                z = fmaf(c[t], xv[j], z);
                ++t;
            }
            maha = fmaf(z, z, maha);
        }
        lp[k] = fmaf(-0.5f, maha, c[44]);
    }

    float mx = fmaxf(fmaxf(lp[0], lp[1]), fmaxf(lp[2], lp[3]));
    float s = __expf(lp[0] - mx) + __expf(lp[1] - mx) +
              __expf(lp[2] - mx) + __expf(lp[3] - mx);
    out[v] = mx + __logf(s);
}

extern "C" void kernel_launch(void* const* d_in, const int* in_sizes, int n_in,
                              void* d_out, int out_size, void* d_ws, size_t ws_size,
                              hipStream_t stream) {
    const float* x       = (const float*)d_in[0];   // [B, N]
    const float* weights = (const float*)d_in[1];   // [K]
    const float* loc     = (const float*)d_in[2];   // [N, K]
    const float* sp      = (const float*)d_in[3];   // [TRI, K]
    float* out = (float*)d_out;
    float* ws  = (float*)d_ws;

    int B = in_sizes[0] / NCH;

    gmm_setup<<<1, 64, 0, stream>>>(weights, loc, sp, ws);

    int threads = 256;
    int blocks = (B + threads - 1) / threads;
    gmm_main<<<blocks, threads, 0, stream>>>(x, ws, out, B);
}